// Round 5
// baseline (121.622 us; speedup 1.0000x reference)
//
#include <hip/hip_runtime.h>

#define FEAT_DIM 256
#define K_NEIGH  32
#define NROWS    20480   // B*S = 2048*10
#define NOUT     1024    // CLIPS*DIM = 8*128
#define NUM_NODES 50000
#define SLICE_DIM 32     // dims per XCD slice
#define NSLICE    8
#define FBLK      1563   // ceil(NUM_NODES/32)

typedef __attribute__((ext_vector_type(8))) short bf16x8;
typedef __attribute__((ext_vector_type(4))) float f32x4;

__device__ __forceinline__ unsigned short f2bf(float f) {
    unsigned int u = __builtin_bit_cast(unsigned int, f);
    u += 0x7fffu + ((u >> 16) & 1u);
    return (unsigned short)(u >> 16);
}
__device__ __forceinline__ float bf2f(unsigned short h) {
    unsigned int u = ((unsigned int)h) << 16;
    return __builtin_bit_cast(float, u);
}
__device__ __forceinline__ void gload16(const void* g, void* l) {
    __builtin_amdgcn_global_load_lds(
        (const __attribute__((address_space(1))) unsigned int*)g,
        (__attribute__((address_space(3))) unsigned int*)l, 16, 0, 0);
}

// ---- weight-only convert (fallback path) ------------------------------------
__global__ __launch_bounds__(256) void wcvt_kernel(const float* __restrict__ w,
                                                   unsigned short* __restrict__ wb) {
    int i = (blockIdx.x * 256 + threadIdx.x) * 4;
    float4 v = *(const float4*)(w + i);
    ushort4 o;
    o.x = f2bf(v.x); o.y = f2bf(v.y); o.z = f2bf(v.z); o.w = f2bf(v.w);
    *(ushort4*)(wb + i) = o;
}

// ---- convert: features -> sliced bf16 fb[8][50000][32]  +  W -> bf16 --------
__global__ __launch_bounds__(256) void cvt_kernel(const float* __restrict__ f,
                                                  unsigned short* __restrict__ fb,
                                                  const float* __restrict__ w,
                                                  unsigned short* __restrict__ wb) {
    int b = blockIdx.x;
    int t = threadIdx.x;
    if (b < FBLK) {
        int g = t >> 5;            // slice 0..7
        int i = t & 31;            // node offset
        int node = b * 32 + i;
        if (node >= NUM_NODES) return;
        const float* src = f + (long)node * FEAT_DIM + g * SLICE_DIM;
        unsigned short o[32];
        #pragma unroll
        for (int j = 0; j < 32; j += 4) {
            float4 v = *(const float4*)(src + j);
            o[j] = f2bf(v.x); o[j+1] = f2bf(v.y); o[j+2] = f2bf(v.z); o[j+3] = f2bf(v.w);
        }
        unsigned short* dst = fb + ((long)g * NUM_NODES + node) * SLICE_DIM;
        #pragma unroll
        for (int j = 0; j < 4; ++j)
            *(bf16x8*)(dst + j * 8) = *(const bf16x8*)(o + j * 8);
    } else {
        int i = ((b - FBLK) * 256 + t) * 4;
        float4 v = *(const float4*)(w + i);
        ushort4 o;
        o.x = f2bf(v.x); o.y = f2bf(v.y); o.z = f2bf(v.z); o.w = f2bf(v.w);
        *(ushort4*)(wb + i) = o;
    }
}

// ---- agg, XCD-sliced (UNCHANGED from R4 for clean measurement) --------------
__global__ __launch_bounds__(256) void agg_sliced(const int* __restrict__ nodes,
                                                  const int* __restrict__ adj,
                                                  const unsigned short* __restrict__ fb,
                                                  unsigned short* __restrict__ feat) {
    int slice = blockIdx.x & 7;
    int chunk = blockIdx.x >> 3;
    int t = threadIdx.x;
    int row = chunk * 64 + (t >> 2);
    int d8 = (t & 3) * 8;
    int node = nodes[row];
    const int* arow = adj + (long)node * K_NEIGH;
    int nbr[K_NEIGH];
    #pragma unroll
    for (int kk = 0; kk < K_NEIGH / 4; ++kk)
        *(int4*)(nbr + kk * 4) = ((const int4*)arow)[kk];

    const unsigned short* base = fb + (long)slice * NUM_NODES * SLICE_DIM + d8;
    float acc[8] = {};
    #pragma unroll
    for (int k = 0; k < K_NEIGH; ++k) {
        bf16x8 v = *(const bf16x8*)(base + (long)nbr[k] * SLICE_DIM);
        #pragma unroll
        for (int j = 0; j < 8; ++j) acc[j] += bf2f((unsigned short)v[j]);
    }
    unsigned short o[8];
    #pragma unroll
    for (int j = 0; j < 8; ++j) o[j] = f2bf(acc[j] * (1.0f / K_NEIGH));
    *(bf16x8*)(feat + (long)row * FEAT_DIM + slice * SLICE_DIM + d8) = *(const bf16x8*)o;
}

// ---- agg from fp32 features (ws fallback) -----------------------------------
__global__ __launch_bounds__(256) void agg_f32_kernel(const int* __restrict__ nodes,
                                                      const int* __restrict__ adj,
                                                      const float* __restrict__ features,
                                                      unsigned short* __restrict__ feat) {
    int row = blockIdx.x;
    int t = threadIdx.x;
    int node = nodes[row];
    const int* arow = adj + (long)node * K_NEIGH;
    float acc = 0.f;
    #pragma unroll
    for (int k = 0; k < K_NEIGH; ++k) {
        long nb = arow[k];
        acc += features[nb * FEAT_DIM + t];
    }
    feat[(long)row * FEAT_DIM + t] = f2bf(acc * (1.0f / K_NEIGH));
}

// ---- GEMM: C = relu(feat x W^T), 128x128 tile, dbuf LDS, XCD-chunked M ------
// 1-D grid of 1280 blocks; xcd = bid&7 owns M-tiles [xcd*20, xcd*20+20) x 8 N.
__global__ __launch_bounds__(256) void gemm_kernel(const unsigned short* __restrict__ A,
                                                   const unsigned short* __restrict__ Bw,
                                                   float* __restrict__ C) {
    __shared__ short As[2][128 * 32];
    __shared__ short Bs[2][128 * 32];

    int bid = blockIdx.x;
    int xcd = bid & 7;
    int i2 = bid >> 3;               // 0..159
    int mt = xcd * 20 + (i2 % 20);   // M-tile 0..159
    int nt = i2 / 20;                // N-tile 0..7

    int t = threadIdx.x;
    int wave = t >> 6, lane = t & 63;
    int wm = wave >> 1, wn = wave & 1;
    int m0 = mt * 128, n0 = nt * 128;
    int lr = lane & 15;
    int lk = (lane >> 4) * 8;

    int srow = t >> 2;
    int sseg = (t & 3) * 8;
    const short* Ag = (const short*)A + (long)(m0 + srow) * FEAT_DIM + sseg;
    const short* Bg = (const short*)Bw + (long)(n0 + srow) * FEAT_DIM + sseg;

    f32x4 acc[4][4] = {};

#define STAGE(bufi, kb) do {                                         \
    gload16(Ag + (kb), &As[bufi][t * 8]);                            \
    gload16(Ag + 64 * FEAT_DIM + (kb), &As[bufi][64 * 32 + t * 8]);  \
    gload16(Bg + (kb), &Bs[bufi][t * 8]);                            \
    gload16(Bg + 64 * FEAT_DIM + (kb), &Bs[bufi][64 * 32 + t * 8]);  \
} while (0)

    STAGE(0, 0);
    asm volatile("s_waitcnt vmcnt(0)" ::: "memory");
    __builtin_amdgcn_s_barrier();

    #pragma unroll
    for (int it = 0; it < 8; ++it) {
        int cur = it & 1;
        if (it < 7) STAGE(cur ^ 1, (it + 1) * 32);

        bf16x8 a[4], b[4];
        #pragma unroll
        for (int i = 0; i < 4; ++i)
            a[i] = *(const bf16x8*)(&As[cur][(wm * 64 + i * 16 + lr) * 32 + lk]);
        #pragma unroll
        for (int j = 0; j < 4; ++j)
            b[j] = *(const bf16x8*)(&Bs[cur][(wn * 64 + j * 16 + lr) * 32 + lk]);
        #pragma unroll
        for (int i = 0; i < 4; ++i)
            #pragma unroll
            for (int j = 0; j < 4; ++j)
                acc[i][j] = __builtin_amdgcn_mfma_f32_16x16x32_bf16(a[i], b[j], acc[i][j], 0, 0, 0);

        if (it < 7) {
            asm volatile("s_waitcnt vmcnt(0)" ::: "memory");
            __builtin_amdgcn_s_barrier();
        }
    }
#undef STAGE

    int crow0 = m0 + wm * 64 + (lane >> 4) * 4;
    int ccol0 = n0 + wn * 64 + lr;
    #pragma unroll
    for (int i = 0; i < 4; ++i)
        #pragma unroll
        for (int j = 0; j < 4; ++j)
            #pragma unroll
            for (int r = 0; r < 4; ++r) {
                float v = acc[i][j][r];
                __builtin_nontemporal_store(v > 0.f ? v : 0.f,
                    &C[(long)(crow0 + i * 16 + r) * NOUT + ccol0 + j * 16]);
            }
}

extern "C" void kernel_launch(void* const* d_in, const int* in_sizes, int n_in,
                              void* d_out, int out_size, void* d_ws, size_t ws_size,
                              hipStream_t stream) {
    const int*   nodes    = (const int*)d_in[0];
    const int*   adj      = (const int*)d_in[1];
    const float* features = (const float*)d_in[2];
    const float* lw       = (const float*)d_in[3];
    float*       out      = (float*)d_out;

    const size_t fbf_elems  = (size_t)NUM_NODES * FEAT_DIM;
    const size_t feat_elems = (size_t)NROWS * FEAT_DIM;
    const size_t need = (fbf_elems + feat_elems + (size_t)NOUT * FEAT_DIM) * 2;

    if (ws_size >= need) {
        unsigned short* fbf  = (unsigned short*)d_ws;
        unsigned short* feat = fbf + fbf_elems;
        unsigned short* wb   = feat + feat_elems;

        cvt_kernel<<<FBLK + (NOUT * FEAT_DIM) / (256 * 4), 256, 0, stream>>>(features, fbf, lw, wb);
        // duplicated launch: measurement round — agg is idempotent, extra run's
        // duration shows up 1:1 in total. (total - 78 - dGemm = agg_dur)
        agg_sliced<<<(NROWS / 64) * NSLICE, 256, 0, stream>>>(nodes, adj, fbf, feat);
        agg_sliced<<<(NROWS / 64) * NSLICE, 256, 0, stream>>>(nodes, adj, fbf, feat);
        gemm_kernel<<<1280, 256, 0, stream>>>(feat, wb, out);
    } else {
        unsigned short* feat = (unsigned short*)d_ws;
        unsigned short* wb   = feat + feat_elems;

        wcvt_kernel<<<(NOUT * FEAT_DIM) / (256 * 4), 256, 0, stream>>>(lw, wb);
        agg_f32_kernel<<<NROWS, 256, 0, stream>>>(nodes, adj, features, feat);
        gemm_kernel<<<1280, 256, 0, stream>>>(feat, wb, out);
    }
}

// Round 6
// 79.248 us; speedup vs baseline: 1.5347x; 1.5347x over previous
//
#include <hip/hip_runtime.h>

#define FEAT_DIM 256
#define K_NEIGH  32
#define NROWS    20480   // B*S = 2048*10
#define NOUT     1024    // CLIPS*DIM = 8*128
#define NUM_NODES 50000
#define SLICE_DIM 64     // dims per slice -> 128 B bf16 granule (full L2 line)
#define NSLICE    4
#define FBLK2     6250   // NUM_NODES/8 nodes per cvt block

typedef __attribute__((ext_vector_type(8))) short bf16x8;
typedef __attribute__((ext_vector_type(4))) float f32x4;

__device__ __forceinline__ unsigned short f2bf(float f) {
    unsigned int u = __builtin_bit_cast(unsigned int, f);
    u += 0x7fffu + ((u >> 16) & 1u);
    return (unsigned short)(u >> 16);
}
__device__ __forceinline__ float bf2f(unsigned short h) {
    unsigned int u = ((unsigned int)h) << 16;
    return __builtin_bit_cast(float, u);
}
__device__ __forceinline__ void gload16(const void* g, void* l) {
    __builtin_amdgcn_global_load_lds(
        (const __attribute__((address_space(1))) unsigned int*)g,
        (__attribute__((address_space(3))) unsigned int*)l, 16, 0, 0);
}

// ---- weight-only convert (fallback path) ------------------------------------
__global__ __launch_bounds__(256) void wcvt_kernel(const float* __restrict__ w,
                                                   unsigned short* __restrict__ wb) {
    int i = (blockIdx.x * 256 + threadIdx.x) * 4;
    float4 v = *(const float4*)(w + i);
    ushort4 o;
    o.x = f2bf(v.x); o.y = f2bf(v.y); o.z = f2bf(v.z); o.w = f2bf(v.w);
    *(ushort4*)(wb + i) = o;
}

// ---- convert: features -> fb[4][50000][64] bf16  +  W -> bf16 ---------------
// 8 lanes = one (node,slice): read 256B dense, write one full 128B line.
__global__ __launch_bounds__(256) void cvt_kernel(const float* __restrict__ f,
                                                  unsigned short* __restrict__ fb,
                                                  const float* __restrict__ w,
                                                  unsigned short* __restrict__ wb) {
    int b = blockIdx.x;
    int t = threadIdx.x;
    if (b < FBLK2) {
        int pair  = t >> 3;             // 0..31: (node,slice) group
        int node  = b * 8 + (pair >> 2);
        int slice = pair & 3;
        int d     = (t & 7) * 8;        // 8 dims per thread
        const float* src = f + (long)node * FEAT_DIM + slice * SLICE_DIM + d;
        float4 v0 = *(const float4*)(src);
        float4 v1 = *(const float4*)(src + 4);
        unsigned short o[8];
        o[0] = f2bf(v0.x); o[1] = f2bf(v0.y); o[2] = f2bf(v0.z); o[3] = f2bf(v0.w);
        o[4] = f2bf(v1.x); o[5] = f2bf(v1.y); o[6] = f2bf(v1.z); o[7] = f2bf(v1.w);
        unsigned short* dst = fb + ((long)slice * NUM_NODES + node) * SLICE_DIM + d;
        *(bf16x8*)dst = *(const bf16x8*)o;
    } else {
        int i = ((b - FBLK2) * 256 + t) * 4;
        float4 v = *(const float4*)(w + i);
        ushort4 o;
        o.x = f2bf(v.x); o.y = f2bf(v.y); o.z = f2bf(v.z); o.w = f2bf(v.w);
        *(ushort4*)(wb + i) = o;
    }
}

// ---- agg: 4 slices of 64 dims; 8 lanes/(row,slice) -> full-line gathers -----
__global__ __launch_bounds__(256) void agg4_kernel(const int* __restrict__ nodes,
                                                   const int* __restrict__ adj,
                                                   const unsigned short* __restrict__ fb,
                                                   unsigned short* __restrict__ feat) {
    int slice = blockIdx.x & 3;
    int chunk = blockIdx.x >> 2;
    int t = threadIdx.x;
    int row = chunk * 32 + (t >> 3);    // 32 rows per block
    int d8 = (t & 7) * 8;               // dim offset within slice
    int node = nodes[row];
    const int* arow = adj + (long)node * K_NEIGH;
    int nbr[K_NEIGH];
    #pragma unroll
    for (int kk = 0; kk < K_NEIGH / 4; ++kk)
        *(int4*)(nbr + kk * 4) = ((const int4*)arow)[kk];   // same-addr dedup in wave

    const unsigned short* base = fb + (long)slice * NUM_NODES * SLICE_DIM + d8;
    float acc[8] = {};
    #pragma unroll
    for (int k = 0; k < K_NEIGH; ++k) {
        bf16x8 v = *(const bf16x8*)(base + (long)nbr[k] * SLICE_DIM);  // 8 lanes = 128B line
        #pragma unroll
        for (int j = 0; j < 8; ++j) acc[j] += bf2f((unsigned short)v[j]);
    }
    unsigned short o[8];
    #pragma unroll
    for (int j = 0; j < 8; ++j) o[j] = f2bf(acc[j] * (1.0f / K_NEIGH));
    *(bf16x8*)(feat + (long)row * FEAT_DIM + slice * SLICE_DIM + d8) = *(const bf16x8*)o;
}

// ---- agg from fp32 features (ws fallback) -----------------------------------
__global__ __launch_bounds__(256) void agg_f32_kernel(const int* __restrict__ nodes,
                                                      const int* __restrict__ adj,
                                                      const float* __restrict__ features,
                                                      unsigned short* __restrict__ feat) {
    int row = blockIdx.x;
    int t = threadIdx.x;
    int node = nodes[row];
    const int* arow = adj + (long)node * K_NEIGH;
    float acc = 0.f;
    #pragma unroll
    for (int k = 0; k < K_NEIGH; ++k) {
        long nb = arow[k];
        acc += features[nb * FEAT_DIM + t];
    }
    feat[(long)row * FEAT_DIM + t] = f2bf(acc * (1.0f / K_NEIGH));
}

// ---- GEMM: C = relu(feat x W^T), 128x128 tile, dbuf LDS, XCD-chunked M ------
__global__ __launch_bounds__(256) void gemm_kernel(const unsigned short* __restrict__ A,
                                                   const unsigned short* __restrict__ Bw,
                                                   float* __restrict__ C) {
    __shared__ short As[2][128 * 32];
    __shared__ short Bs[2][128 * 32];

    int bid = blockIdx.x;
    int xcd = bid & 7;
    int i2 = bid >> 3;               // 0..159
    int mt = xcd * 20 + (i2 % 20);   // M-tile 0..159
    int nt = i2 / 20;                // N-tile 0..7

    int t = threadIdx.x;
    int wave = t >> 6, lane = t & 63;
    int wm = wave >> 1, wn = wave & 1;
    int m0 = mt * 128, n0 = nt * 128;
    int lr = lane & 15;
    int lk = (lane >> 4) * 8;

    int srow = t >> 2;
    int sseg = (t & 3) * 8;
    const short* Ag = (const short*)A + (long)(m0 + srow) * FEAT_DIM + sseg;
    const short* Bg = (const short*)Bw + (long)(n0 + srow) * FEAT_DIM + sseg;

    f32x4 acc[4][4] = {};

#define STAGE(bufi, kb) do {                                         \
    gload16(Ag + (kb), &As[bufi][t * 8]);                            \
    gload16(Ag + 64 * FEAT_DIM + (kb), &As[bufi][64 * 32 + t * 8]);  \
    gload16(Bg + (kb), &Bs[bufi][t * 8]);                            \
    gload16(Bg + 64 * FEAT_DIM + (kb), &Bs[bufi][64 * 32 + t * 8]);  \
} while (0)

    STAGE(0, 0);
    asm volatile("s_waitcnt vmcnt(0)" ::: "memory");
    __builtin_amdgcn_s_barrier();

    #pragma unroll
    for (int it = 0; it < 8; ++it) {
        int cur = it & 1;
        if (it < 7) STAGE(cur ^ 1, (it + 1) * 32);

        bf16x8 a[4], b[4];
        #pragma unroll
        for (int i = 0; i < 4; ++i)
            a[i] = *(const bf16x8*)(&As[cur][(wm * 64 + i * 16 + lr) * 32 + lk]);
        #pragma unroll
        for (int j = 0; j < 4; ++j)
            b[j] = *(const bf16x8*)(&Bs[cur][(wn * 64 + j * 16 + lr) * 32 + lk]);
        #pragma unroll
        for (int i = 0; i < 4; ++i)
            #pragma unroll
            for (int j = 0; j < 4; ++j)
                acc[i][j] = __builtin_amdgcn_mfma_f32_16x16x32_bf16(a[i], b[j], acc[i][j], 0, 0, 0);

        if (it < 7) {
            asm volatile("s_waitcnt vmcnt(0)" ::: "memory");
            __builtin_amdgcn_s_barrier();
        }
    }
#undef STAGE

    int crow0 = m0 + wm * 64 + (lane >> 4) * 4;
    int ccol0 = n0 + wn * 64 + lr;
    #pragma unroll
    for (int i = 0; i < 4; ++i)
        #pragma unroll
        for (int j = 0; j < 4; ++j)
            #pragma unroll
            for (int r = 0; r < 4; ++r) {
                float v = acc[i][j][r];
                __builtin_nontemporal_store(v > 0.f ? v : 0.f,
                    &C[(long)(crow0 + i * 16 + r) * NOUT + ccol0 + j * 16]);
            }
}

extern "C" void kernel_launch(void* const* d_in, const int* in_sizes, int n_in,
                              void* d_out, int out_size, void* d_ws, size_t ws_size,
                              hipStream_t stream) {
    const int*   nodes    = (const int*)d_in[0];
    const int*   adj      = (const int*)d_in[1];
    const float* features = (const float*)d_in[2];
    const float* lw       = (const float*)d_in[3];
    float*       out      = (float*)d_out;

    const size_t fbf_elems  = (size_t)NUM_NODES * FEAT_DIM;
    const size_t feat_elems = (size_t)NROWS * FEAT_DIM;
    const size_t need = (fbf_elems + feat_elems + (size_t)NOUT * FEAT_DIM) * 2;

    if (ws_size >= need) {
        unsigned short* fbf  = (unsigned short*)d_ws;
        unsigned short* feat = fbf + fbf_elems;
        unsigned short* wb   = feat + feat_elems;

        cvt_kernel<<<FBLK2 + (NOUT * FEAT_DIM) / (256 * 4), 256, 0, stream>>>(features, fbf, lw, wb);
        agg4_kernel<<<(NROWS / 32) * NSLICE, 256, 0, stream>>>(nodes, adj, fbf, feat);
        gemm_kernel<<<1280, 256, 0, stream>>>(feat, wb, out);
    } else {
        unsigned short* feat = (unsigned short*)d_ws;
        unsigned short* wb   = feat + feat_elems;

        wcvt_kernel<<<(NOUT * FEAT_DIM) / (256 * 4), 256, 0, stream>>>(lw, wb);
        agg_f32_kernel<<<NROWS, 256, 0, stream>>>(nodes, adj, features, feat);
        gemm_kernel<<<1280, 256, 0, stream>>>(feat, wb, out);
    }
}